// Round 2
// baseline (299.847 us; speedup 1.0000x reference)
//
#include <hip/hip_runtime.h>
#include <hip/hip_bf16.h>

#define BATCH 16
#define CIN   512
#define HW    3136
#define CM    512
#define CN    128
#define CBV   256

typedef short short8 __attribute__((ext_vector_type(8)));
typedef float f32x4  __attribute__((ext_vector_type(4)));

#define MFMA(a,b,c) __builtin_amdgcn_mfma_f32_16x16x32_bf16((a),(b),(c),0,0,0)

// convert 8 consecutive fp32 -> 8 bf16, store as one b128 to LDS
__device__ __forceinline__ void cvt_store8(__bf16* dst, const float* src) {
  const f32x4 a = *(const f32x4*)src;
  const f32x4 b = *(const f32x4*)(src + 4);
  __attribute__((aligned(16))) __bf16 t[8];
  t[0] = (__bf16)a[0]; t[1] = (__bf16)a[1]; t[2] = (__bf16)a[2]; t[3] = (__bf16)a[3];
  t[4] = (__bf16)b[0]; t[5] = (__bf16)b[1]; t[6] = (__bf16)b[2]; t[7] = (__bf16)b[3];
  *(uint4*)dst = *(uint4*)t;
}

// ---------------------------------------------------------------------------
// Kernel 1: BV[b][n][s] = (n<128 ? wB : wV) @ x[b] + bias  (M=256,K=512,N=3136)
// fp32 inputs converted to bf16 at staging; fp32 accumulate; bf16 out (internal)
// ---------------------------------------------------------------------------
__global__ __launch_bounds__(256) void conv_bv_kernel(
    const float* __restrict__ x,
    const float* __restrict__ wB, const float* __restrict__ bB,
    const float* __restrict__ wV, const float* __restrict__ bV,
    __bf16* __restrict__ BV)
{
  const int s0  = blockIdx.x * 64;
  const int b   = blockIdx.y;
  const int tid = threadIdx.x;
  const int lane = tid & 63;
  const int w    = tid >> 6;
  const int l15  = lane & 15;
  const int q    = lane >> 4;

  __shared__ __attribute__((aligned(16))) __bf16 Wt[256*72]; // A tile [n][k]
  __shared__ __attribute__((aligned(16))) __bf16 Xt[64*72];  // B tile [s][k] (x^T)

  f32x4 acc[4][4] = {};

  const float* xb = x + (size_t)b * CIN * HW;
  const int colg = tid & 7, row0 = tid >> 3;   // staging map
  const int s_l = tid & 63, cb = tid >> 6;     // transpose-gather map

  for (int k0 = 0; k0 < CIN; k0 += 64) {
    // stage W (256x64) with fp32->bf16 convert
    #pragma unroll
    for (int p = 0; p < 8; ++p) {
      int row = row0 + 32*p;
      const float* src = (row < 128) ? (wB + row*512) : (wV + (row-128)*512);
      cvt_store8(&Wt[row*72 + colg*8], src + k0 + colg*8);
    }
    // stage x^T (64s x 64k): lane-coalesced scalar fp32 loads -> bf16 b128 write
    #pragma unroll
    for (int p = 0; p < 2; ++p) {
      int cg = cb + 4*p;
      __attribute__((aligned(16))) __bf16 tmp[8];
      #pragma unroll
      for (int j = 0; j < 8; ++j)
        tmp[j] = (__bf16)xb[(size_t)(k0 + cg*8 + j)*HW + s0 + s_l];
      *(uint4*)&Xt[s_l*72 + cg*8] = *(uint4*)tmp;
    }
    __syncthreads();
    #pragma unroll
    for (int kk = 0; kk < 2; ++kk) {
      short8 a[4], bb[4];
      #pragma unroll
      for (int mi = 0; mi < 4; ++mi)
        a[mi] = *(short8*)&Wt[(w*64 + mi*16 + l15)*72 + kk*32 + q*8];
      #pragma unroll
      for (int si = 0; si < 4; ++si)
        bb[si] = *(short8*)&Xt[(si*16 + l15)*72 + kk*32 + q*8];
      #pragma unroll
      for (int mi = 0; mi < 4; ++mi)
        #pragma unroll
        for (int si = 0; si < 4; ++si)
          acc[mi][si] = MFMA(a[mi], bb[si], acc[mi][si]);
    }
    __syncthreads();
  }

  const size_t outb = (size_t)b * CBV * HW;
  #pragma unroll
  for (int mi = 0; mi < 4; ++mi)
    #pragma unroll
    for (int si = 0; si < 4; ++si) {
      int s = s0 + si*16 + l15;
      #pragma unroll
      for (int r = 0; r < 4; ++r) {
        int nch = w*64 + mi*16 + q*4 + r;
        float bias = (nch < CN) ? bB[nch] : bV[nch-CN];
        BV[outb + (size_t)nch*HW + s] = (__bf16)(acc[mi][si][r] + bias);
      }
    }
}

// ---------------------------------------------------------------------------
// Kernel 2: in-place softmax over s for BV rows n in [0,128)  -> attB
// ---------------------------------------------------------------------------
__global__ __launch_bounds__(256) void softmax_b_kernel(__bf16* __restrict__ BV)
{
  const int n = blockIdx.x, b = blockIdx.y;
  __bf16* row = BV + ((size_t)b*CBV + n)*HW;
  const int tid = threadIdx.x;

  float v[13];
  float mx = -1e30f;
  #pragma unroll
  for (int i = 0; i < 13; ++i) {
    int idx = tid + i*256;
    v[i] = (idx < HW) ? (float)row[idx] : -1e30f;
    mx = fmaxf(mx, v[i]);
  }
  #pragma unroll
  for (int off = 32; off > 0; off >>= 1) mx = fmaxf(mx, __shfl_down(mx, off));
  __shared__ float redm[4], reds[4];
  if ((tid & 63) == 0) redm[tid >> 6] = mx;
  __syncthreads();
  float m = fmaxf(fmaxf(redm[0], redm[1]), fmaxf(redm[2], redm[3]));

  float sum = 0.f;
  #pragma unroll
  for (int i = 0; i < 13; ++i) { v[i] = __expf(v[i] - m); sum += v[i]; }
  #pragma unroll
  for (int off = 32; off > 0; off >>= 1) sum += __shfl_down(sum, off);
  if ((tid & 63) == 0) reds[tid >> 6] = sum;
  __syncthreads();
  float inv = 1.0f / (reds[0] + reds[1] + reds[2] + reds[3]);

  #pragma unroll
  for (int i = 0; i < 13; ++i) {
    int idx = tid + i*256;
    if (idx < HW) row[idx] = (__bf16)(v[i] * inv);
  }
}

// ---------------------------------------------------------------------------
// Kernel 3: softmax over n (128 ch) per spatial s; writes TRANSPOSED attVT[b][s][n]
// ---------------------------------------------------------------------------
__global__ __launch_bounds__(256) void softmax_v_t_kernel(
    const __bf16* __restrict__ BV, __bf16* __restrict__ attVT)
{
  const int s0 = blockIdx.x * 64, b = blockIdx.y;
  const int tid = threadIdx.x;
  const int s_l = tid & 63, jg = tid >> 6;
  const __bf16* vb = BV + ((size_t)b*CBV + CN)*HW + s0 + s_l;

  float v[32];
  float mx = -1e30f;
  #pragma unroll
  for (int i = 0; i < 32; ++i) {
    v[i] = (float)vb[(size_t)(jg*32 + i)*HW];
    mx = fmaxf(mx, v[i]);
  }
  __shared__ float red[4][64];
  red[jg][s_l] = mx;
  __syncthreads();
  float m = fmaxf(fmaxf(red[0][s_l], red[1][s_l]), fmaxf(red[2][s_l], red[3][s_l]));
  float sum = 0.f;
  #pragma unroll
  for (int i = 0; i < 32; ++i) { v[i] = __expf(v[i] - m); sum += v[i]; }
  __syncthreads();
  red[jg][s_l] = sum;
  __syncthreads();
  float inv = 1.0f / (red[0][s_l] + red[1][s_l] + red[2][s_l] + red[3][s_l]);

  __shared__ __attribute__((aligned(16))) __bf16 T[64*136];
  #pragma unroll
  for (int u = 0; u < 4; ++u) {
    __attribute__((aligned(16))) __bf16 tmp[8];
    #pragma unroll
    for (int j = 0; j < 8; ++j) tmp[j] = (__bf16)(v[u*8 + j] * inv);
    *(uint4*)&T[s_l*136 + jg*32 + u*8] = *(uint4*)tmp;
  }
  __syncthreads();
  __bf16* dst = attVT + ((size_t)b*HW + s0)*CN;
  const int g = tid & 15, r0 = tid >> 4;
  #pragma unroll
  for (int p = 0; p < 4; ++p) {
    int row = r0 + 16*p;
    *(uint4*)&dst[row*CN + g*8] = *(uint4*)&T[row*136 + g*8];
  }
}

// ---------------------------------------------------------------------------
// Kernel 4: H[b][c][n] += sum_s x[b][c][s]*attB[b][n][s]
// tile 128c x 128n, split-K=7 (s in chunks of 448), fp32 atomic accumulate
// ---------------------------------------------------------------------------
__global__ __launch_bounds__(256) void h_gemm_kernel(
    const float* __restrict__ x, const __bf16* __restrict__ attB,
    float* __restrict__ H)
{
  const int c0 = blockIdx.x * 128, b = blockIdx.y, kc = blockIdx.z;
  const int tid = threadIdx.x, lane = tid & 63, w = tid >> 6;
  const int l15 = lane & 15, q = lane >> 4;

  __shared__ __attribute__((aligned(16))) __bf16 At[128*72];  // x tile [c][s] (bf16)
  __shared__ __attribute__((aligned(16))) __bf16 Bt[128*72];  // attB tile [n][s]
  f32x4 acc[8][2] = {};

  const float* xb = x + ((size_t)b*CIN + c0)*HW;
  const __bf16* ab = attB + (size_t)b*CBV*HW;
  const int colg = tid & 7, row0 = tid >> 3;

  for (int ki = 0; ki < 7; ++ki) {
    int k0 = kc*448 + ki*64;
    #pragma unroll
    for (int p = 0; p < 4; ++p) {
      int row = row0 + 32*p;
      cvt_store8(&At[row*72 + colg*8], xb + (size_t)row*HW + k0 + colg*8);
    }
    #pragma unroll
    for (int p = 0; p < 4; ++p) {
      int row = row0 + 32*p;
      *(uint4*)&Bt[row*72 + colg*8] = *(const uint4*)(ab + (size_t)row*HW + k0 + colg*8);
    }
    __syncthreads();
    #pragma unroll
    for (int kk = 0; kk < 2; ++kk) {
      short8 a[8], bb[2];
      #pragma unroll
      for (int mi = 0; mi < 8; ++mi)
        a[mi] = *(short8*)&At[(mi*16 + l15)*72 + kk*32 + q*8];
      #pragma unroll
      for (int ni = 0; ni < 2; ++ni)
        bb[ni] = *(short8*)&Bt[(w*32 + ni*16 + l15)*72 + kk*32 + q*8];
      #pragma unroll
      for (int mi = 0; mi < 8; ++mi)
        #pragma unroll
        for (int ni = 0; ni < 2; ++ni)
          acc[mi][ni] = MFMA(a[mi], bb[ni], acc[mi][ni]);
    }
    __syncthreads();
  }

  float* Hb = H + (size_t)b*CIN*CN;
  #pragma unroll
  for (int mi = 0; mi < 8; ++mi)
    #pragma unroll
    for (int ni = 0; ni < 2; ++ni)
      #pragma unroll
      for (int r = 0; r < 4; ++r) {
        int c = c0 + mi*16 + q*4 + r;
        int n = w*32 + ni*16 + l15;
        atomicAdd(&Hb[c*CN + n], acc[mi][ni][r]);
      }
}

// ---------------------------------------------------------------------------
// Kernel 5: G[b] = wA @ H[b] + bA  (M=512 in 64-tiles, N=128, K=512) -> bf16
// ---------------------------------------------------------------------------
__global__ __launch_bounds__(256) void g_gemm_kernel(
    const float* __restrict__ wA, const float* __restrict__ bA,
    const float* __restrict__ H, __bf16* __restrict__ G)
{
  const int m0 = blockIdx.x * 64, b = blockIdx.y;
  const int tid = threadIdx.x, lane = tid & 63, w = tid >> 6;
  const int l15 = lane & 15, q = lane >> 4;

  __shared__ __attribute__((aligned(16))) __bf16 At[64*72];   // wA tile [m][c]
  __shared__ __attribute__((aligned(16))) __bf16 Bt[128*72];  // H^T tile [n][c]
  f32x4 acc[4][2] = {};

  const float* Hb = H + (size_t)b*CIN*CN;
  const int colg = tid & 7, row0 = tid >> 3;
  const int nn = tid & 127, gh = tid >> 7;

  for (int k0 = 0; k0 < CIN; k0 += 64) {
    #pragma unroll
    for (int p = 0; p < 2; ++p) {
      int row = row0 + 32*p;
      cvt_store8(&At[row*72 + colg*8], wA + (size_t)(m0+row)*CIN + k0 + colg*8);
    }
    #pragma unroll
    for (int p = 0; p < 4; ++p) {
      int g = gh + 2*p;
      __attribute__((aligned(16))) __bf16 tmp[8];
      #pragma unroll
      for (int j = 0; j < 8; ++j)
        tmp[j] = (__bf16)Hb[(size_t)(k0 + g*8 + j)*CN + nn];
      *(uint4*)&Bt[nn*72 + g*8] = *(uint4*)tmp;
    }
    __syncthreads();
    #pragma unroll
    for (int kk = 0; kk < 2; ++kk) {
      short8 a[4], bb[2];
      #pragma unroll
      for (int mi = 0; mi < 4; ++mi)
        a[mi] = *(short8*)&At[(mi*16 + l15)*72 + kk*32 + q*8];
      #pragma unroll
      for (int ni = 0; ni < 2; ++ni)
        bb[ni] = *(short8*)&Bt[(w*32 + ni*16 + l15)*72 + kk*32 + q*8];
      #pragma unroll
      for (int mi = 0; mi < 4; ++mi)
        #pragma unroll
        for (int ni = 0; ni < 2; ++ni)
          acc[mi][ni] = MFMA(a[mi], bb[ni], acc[mi][ni]);
    }
    __syncthreads();
  }

  #pragma unroll
  for (int mi = 0; mi < 4; ++mi)
    #pragma unroll
    for (int ni = 0; ni < 2; ++ni)
      #pragma unroll
      for (int r = 0; r < 4; ++r) {
        int m = m0 + mi*16 + q*4 + r;
        int n = w*32 + ni*16 + l15;
        G[((size_t)b*CM + m)*CN + n] = (__bf16)(acc[mi][ni][r] + bA[m]);
      }
}

// ---------------------------------------------------------------------------
// Kernel 6: Z[b][m][s] = sum_n G[b][m][n] * attVT[b][s][n]  -> fp32 output
// block tile 128m x 64s, K=128 single stage
// ---------------------------------------------------------------------------
__global__ __launch_bounds__(256) void z_gemm_kernel(
    const __bf16* __restrict__ G, const __bf16* __restrict__ attVT,
    float* __restrict__ out)
{
  const int m0 = blockIdx.x * 128, s0 = blockIdx.y * 64, b = blockIdx.z;
  const int tid = threadIdx.x, lane = tid & 63, w = tid >> 6;
  const int l15 = lane & 15, q = lane >> 4;

  __shared__ __attribute__((aligned(16))) __bf16 At[128*136]; // G tile [m][n]
  __shared__ __attribute__((aligned(16))) __bf16 Bt[64*136];  // attVT tile [s][n]

  const __bf16* Gb = G + ((size_t)b*CM + m0)*CN;
  const __bf16* Vb = attVT + ((size_t)b*HW + s0)*CN;
  const int g = tid & 15, r0 = tid >> 4;
  #pragma unroll
  for (int p = 0; p < 8; ++p) {
    int row = r0 + 16*p;
    *(uint4*)&At[row*136 + g*8] = *(const uint4*)(Gb + (size_t)row*CN + g*8);
  }
  #pragma unroll
  for (int p = 0; p < 4; ++p) {
    int row = r0 + 16*p;
    *(uint4*)&Bt[row*136 + g*8] = *(const uint4*)(Vb + (size_t)row*CN + g*8);
  }
  __syncthreads();

  f32x4 acc[8] = {};
  #pragma unroll
  for (int kk = 0; kk < 4; ++kk) {
    short8 bb = *(short8*)&Bt[(w*16 + l15)*136 + kk*32 + q*8];
    #pragma unroll
    for (int mi = 0; mi < 8; ++mi) {
      short8 a = *(short8*)&At[(mi*16 + l15)*136 + kk*32 + q*8];
      acc[mi] = MFMA(a, bb, acc[mi]);
    }
  }

  const int s = s0 + w*16 + l15;
  #pragma unroll
  for (int mi = 0; mi < 8; ++mi)
    #pragma unroll
    for (int r = 0; r < 4; ++r) {
      int m = m0 + mi*16 + q*4 + r;
      out[((size_t)b*CM + m)*HW + s] = acc[mi][r];
    }
}

// ---------------------------------------------------------------------------
extern "C" void kernel_launch(void* const* d_in, const int* in_sizes, int n_in,
                              void* d_out, int out_size, void* d_ws, size_t ws_size,
                              hipStream_t stream)
{
  (void)in_sizes; (void)n_in; (void)out_size; (void)ws_size;
  const float* x  = (const float*)d_in[0];
  const float* wA = (const float*)d_in[1];
  const float* bA = (const float*)d_in[2];
  const float* wB = (const float*)d_in[3];
  const float* bB = (const float*)d_in[4];
  const float* wV = (const float*)d_in[5];
  const float* bV = (const float*)d_in[6];
  // d_in[7] is K == 1 (identity reshapes) — unused.
  float* out = (float*)d_out;

  char* ws = (char*)d_ws;
  const size_t szBV    = (size_t)BATCH*CBV*HW*2;   // 25,690,112
  const size_t szAttVT = (size_t)BATCH*HW*CN*2;    // 12,845,056
  const size_t szH     = (size_t)BATCH*CIN*CN*4;   //  4,194,304
  __bf16* BV    = (__bf16*)(ws);
  __bf16* attVT = (__bf16*)(ws + szBV);
  float*  H     = (float*) (ws + szBV + szAttVT);
  __bf16* G     = (__bf16*)(ws + szBV + szAttVT + szH);

  conv_bv_kernel    <<<dim3(49,16),  256, 0, stream>>>(x, wB, bB, wV, bV, BV);
  softmax_b_kernel  <<<dim3(128,16), 256, 0, stream>>>(BV);
  softmax_v_t_kernel<<<dim3(49,16),  256, 0, stream>>>(BV, attVT);
  hipMemsetAsync(H, 0, szH, stream);
  h_gemm_kernel     <<<dim3(4,16,7), 256, 0, stream>>>(x, BV, H);
  g_gemm_kernel     <<<dim3(8,16),   256, 0, stream>>>(wA, bA, H, G);
  z_gemm_kernel     <<<dim3(4,49,16),256, 0, stream>>>(G, attVT, out);
}